// Round 1
// 622.376 us; speedup vs baseline: 2.2950x; 2.2950x over previous
//
#include <hip/hip_runtime.h>
#include <stdint.h>

#define GRID_RES 64
#define NPTS 1048576
#define CH 64
#define IMG 512
#define BATCH 4
#define NBINS 1024              // fallback path: 4 batches x 16 x 16 tiles of 32x32 px
#define NBLK_D (NPTS / 4)       // fallback gather: 4 points (waves) per 256-thr block
#define CHUNKS_PER_XCD (NBLK_D / 8)

struct Rec { float di, dj; uint32_t meta, pt; };

__device__ __forceinline__ void project_point(
    const int4 cd, const float* __restrict__ Km, const float* __restrict__ Pm,
    float& di, float& dj, int& i0, int& i1, int& j0, int& j1, int& b, float& cz_out)
{
    b = cd.x;
    const float s = 2.0f / (GRID_RES - 1);
    float wx = (float)cd.y * s - 1.0f;
    float wy = (float)cd.z * s - 1.0f;
    float wz = (float)cd.w * s - 1.0f;

    float cx = Pm[0]*wx  + Pm[1]*wy  + Pm[2]*wz  + Pm[3];
    float cy = Pm[4]*wx  + Pm[5]*wy  + Pm[6]*wz  + Pm[7];
    float cz = Pm[8]*wx  + Pm[9]*wy  + Pm[10]*wz + Pm[11];
    float cw = Pm[12]*wx + Pm[13]*wy + Pm[14]*wz + Pm[15];
    cx = cx / cw; cy = cy / cw; cz = cz / cw;

    float ix = Km[0]*cx + Km[1]*cy + Km[2]*cz;
    float iy = Km[3]*cx + Km[4]*cy + Km[5]*cz;
    float iz = Km[6]*cx + Km[7]*cy + Km[8]*cz;
    float x = ix / iz;
    float y = iy / iz;

    float fi = floorf(y);
    float fj = floorf(x);
    di = y - fi;
    dj = x - fj;
    i0 = min(max((int)fi, 0), IMG - 1);
    i1 = min(max((int)fi + 1, 0), IMG - 1);
    j0 = min(max((int)fj, 0), IMG - 1);
    j1 = min(max((int)fj + 1, 0), IMG - 1);
    cz_out = cz;
}

// ===========================================================================
// NEW PATH: project → transpose features to (B,H,W,C) → coalesced gather
// ===========================================================================

// ---- Pass P: project all points, write per-point record + depth ----------
__global__ __launch_bounds__(256) void pass_project(
    const int* __restrict__ coords, const float* __restrict__ Km,
    const float* __restrict__ Pm, Rec* __restrict__ tmp,
    float* __restrict__ out_depth)
{
    int pt = blockIdx.x * 256 + threadIdx.x;
    const int4 cd = ((const int4*)coords)[pt];
    float di, dj, cz; int i0, i1, j0, j1, b;
    project_point(cd, Km, Pm, di, dj, i0, i1, j0, j1, b, cz);

    Rec r;
    r.di = di; r.dj = dj;
    r.meta = ((uint32_t)b << 20) | ((uint32_t)i0 << 11) | ((uint32_t)j0 << 2)
           | ((uint32_t)(i1 - i0) << 1) | (uint32_t)(j1 - j0);
    r.pt = (uint32_t)pt;
    tmp[pt] = r;
    out_depth[pt] = cz;
}

// ---- Pass T: transpose (B,C,H,W) -> (B,H,W,C) via LDS tile ---------------
// Block = one (b, row i, 128-px quarter). Tile = 128 px x 64 ch.
// Loads: float2/lane, fully coalesced along W. Stores: float4/lane (16
// consecutive lanes cover the 64 channels of one pixel), fully coalesced.
// LDS row pad 65 -> at most 4-way write conflict (cheap), 2-way read (free).
__global__ __launch_bounds__(256) void pass_transpose(
    const float* __restrict__ feat, float* __restrict__ featT)
{
    __shared__ float lds[128 * 65];
    const int t   = threadIdx.x;
    const int blk = blockIdx.x;
    const int q = blk & 3;             // which 128-px quarter
    const int i = (blk >> 2) & 511;    // image row
    const int b = blk >> 11;           // batch
    const int j0 = q << 7;

    const int lane  = t & 63;
    const int px2   = lane << 1;
    const int cbase = t >> 6;          // 0..3
    const float* src = feat + ((size_t)(b * CH + cbase) << 18)
                            + ((size_t)i << 9) + j0 + px2;
    #pragma unroll
    for (int k = 0; k < 16; ++k) {
        int c = cbase + (k << 2);
        float2 v = *(const float2*)(src + ((size_t)(k << 2) << 18));
        lds[(px2 + 0) * 65 + c] = v.x;
        lds[(px2 + 1) * 65 + c] = v.y;
    }
    __syncthreads();

    const int c4    = (t & 15) << 2;
    const int pbase = t >> 4;          // 0..15
    float* dst = featT + ((size_t)b << 24) + ((size_t)i << 15)
                       + ((size_t)j0 << 6) + c4;
    #pragma unroll
    for (int m = 0; m < 8; ++m) {
        int pix = pbase + (m << 4);
        float4 w;
        w.x = lds[pix * 65 + c4 + 0];
        w.y = lds[pix * 65 + c4 + 1];
        w.z = lds[pix * 65 + c4 + 2];
        w.w = lds[pix * 65 + c4 + 3];
        *(float4*)(dst + ((size_t)pix << 6)) = w;
    }
}

// ---- Pass G: coalesced gather — wave = 4 points, lane = channel ----------
// featT is channels-last: each corner load = 256 B contiguous per wave
// (4 cache lines) instead of 64 scattered lines. 16 independent loads in
// flight per wave via the unrolled 4-point loop.
__global__ __launch_bounds__(256) void pass_gather_t(
    const Rec* __restrict__ recs, const float* __restrict__ featT,
    float* __restrict__ out_feat)
{
    const uint32_t wave = (blockIdx.x << 2) + (threadIdx.x >> 6);
    const uint32_t p0 = wave << 2;
    const int c = threadIdx.x & 63;

    #pragma unroll
    for (int u = 0; u < 4; ++u) {
        Rec r = recs[p0 + u];                 // same addr across wave → broadcast
        uint32_t m = r.meta;
        int j1d = m & 1;
        int i1d = (m >> 1) & 1;
        int j0  = (m >> 2) & 511;
        int i0  = (m >> 11) & 511;
        int b   = m >> 20;

        const float* base = featT + ((size_t)b << 24) + ((size_t)i0 << 15)
                                  + ((size_t)j0 << 6) + c;
        float f00 = base[0];
        float f01 = base[j1d << 6];
        float f10 = base[i1d << 15];
        float f11 = base[(i1d << 15) + (j1d << 6)];

        float omdi = 1.0f - r.di;
        float mj  = omdi * f00 + r.di * f10;
        float mjp = omdi * f01 + r.di * f11;
        float res = (1.0f - r.dj) * mj + r.dj * mjp;

        out_feat[((size_t)(p0 + u) << 6) + c] = res;
    }
}

// ===========================================================================
// FALLBACK 1: previous binned pipeline (ws >= 32 MB but < 284 MB)
// ===========================================================================

__global__ void pass_zero(uint32_t* counts) {
    counts[threadIdx.x] = 0;   // 1 block x 1024 threads
}

__global__ __launch_bounds__(256) void pass_hist(
    const int* __restrict__ coords, const float* __restrict__ Km,
    const float* __restrict__ Pm, uint32_t* __restrict__ counts,
    Rec* __restrict__ tmp, float* __restrict__ out_depth)
{
    __shared__ uint32_t h[NBINS];
    for (int i = threadIdx.x; i < NBINS; i += 256) h[i] = 0;
    __syncthreads();

    int pt = blockIdx.x * 256 + threadIdx.x;
    const int4 cd = ((const int4*)coords)[pt];
    float di, dj, cz; int i0, i1, j0, j1, b;
    project_point(cd, Km, Pm, di, dj, i0, i1, j0, j1, b, cz);

    Rec r;
    r.di = di; r.dj = dj;
    r.meta = ((uint32_t)b << 20) | ((uint32_t)i0 << 11) | ((uint32_t)j0 << 2)
           | ((uint32_t)(i1 - i0) << 1) | (uint32_t)(j1 - j0);
    r.pt = (uint32_t)pt;
    tmp[pt] = r;
    out_depth[pt] = cz;

    int bin = (b << 8) | ((i0 >> 5) << 4) | (j0 >> 5);
    atomicAdd(&h[bin], 1u);
    __syncthreads();
    for (int i = threadIdx.x; i < NBINS; i += 256)
        if (h[i]) atomicAdd(&counts[i], h[i]);
}

__global__ void pass_scan(const uint32_t* __restrict__ counts, uint32_t* __restrict__ cursor) {
    __shared__ uint32_t a[NBINS];
    int t = threadIdx.x;            // 1 block x 1024 threads
    a[t] = counts[t];
    __syncthreads();
    for (int off = 1; off < NBINS; off <<= 1) {
        uint32_t v = a[t];
        uint32_t add = (t >= off) ? a[t - off] : 0u;
        __syncthreads();
        a[t] = v + add;
        __syncthreads();
    }
    cursor[t] = (t == 0) ? 0u : a[t - 1];
}

__global__ __launch_bounds__(256) void pass_scatter(
    const Rec* __restrict__ tmp, uint32_t* __restrict__ cursor, Rec* __restrict__ recs)
{
    int pt = blockIdx.x * 256 + threadIdx.x;
    Rec r = tmp[pt];
    int i0 = (r.meta >> 11) & 511;
    int j0 = (r.meta >> 2) & 511;
    int b  = r.meta >> 20;
    int bin = (b << 8) | ((i0 >> 5) << 4) | (j0 >> 5);
    uint32_t pos = atomicAdd(&cursor[bin], 1u);
    recs[pos] = r;
}

__global__ __launch_bounds__(256) void pass_gather(
    const Rec* __restrict__ recs, const float* __restrict__ feat,
    float* __restrict__ out_feat)
{
    uint32_t bi = blockIdx.x;
    uint32_t chunk = (bi & 7u) * CHUNKS_PER_XCD + (bi >> 3);
    uint32_t p = chunk * 4u + (threadIdx.x >> 6);
    int c = threadIdx.x & 63;

    Rec r = recs[p];
    int j1d = r.meta & 1;
    int i1d = (r.meta >> 1) & 1;
    int j0  = (r.meta >> 2) & 511;
    int i0  = (r.meta >> 11) & 511;
    int b   = r.meta >> 20;

    const float* base = feat + ((size_t)(b * CH + c) << 18);
    const float* r0 = base + (i0 << 9);
    const float* r1 = r0 + (i1d << 9);
    float f00 = r0[j0];
    float f01 = r0[j0 + j1d];
    float f10 = r1[j0];
    float f11 = r1[j0 + j1d];

    float omdi = 1.0f - r.di;
    float mj  = omdi * f00 + r.di * f10;
    float mjp = omdi * f01 + r.di * f11;
    float res = (1.0f - r.dj) * mj + r.dj * mjp;

    out_feat[(size_t)r.pt * CH + c] = res;
}

// ===========================================================================
// FALLBACK 2: round-1 kernel (ws too small for anything)
// ===========================================================================
__global__ __launch_bounds__(256) void gs_tok(
    const int* __restrict__ coords, const float* __restrict__ feat,
    const float* __restrict__ Km, const float* __restrict__ Pm,
    float* __restrict__ out_feat, float* __restrict__ out_depth)
{
    int t = blockIdx.x * blockDim.x + threadIdx.x;
    int point = t >> 6;
    int c = t & 63;
    if (point >= NPTS) return;
    const int4 cd = ((const int4*)coords)[point];
    float di, dj, cz; int i0, i1, j0, j1, b;
    project_point(cd, Km, Pm, di, dj, i0, i1, j0, j1, b, cz);
    const float* base = feat + ((size_t)(b * CH + c) << 18);
    const float* r0 = base + (i0 << 9);
    const float* r1 = base + (i1 << 9);
    float f00 = r0[j0], f01 = r0[j1], f10 = r1[j0], f11 = r1[j1];
    float omdi = 1.0f - di;
    float mj  = omdi * f00 + di * f10;
    float mjp = omdi * f01 + di * f11;
    float res = (1.0f - dj) * mj + dj * mjp;
    out_feat[(size_t)point * CH + c] = res;
    if (c == 0) out_depth[point] = cz;
}

extern "C" void kernel_launch(void* const* d_in, const int* in_sizes, int n_in,
                              void* d_out, int out_size, void* d_ws, size_t ws_size,
                              hipStream_t stream)
{
    const int*   coords = (const int*)d_in[0];
    const float* feat   = (const float*)d_in[1];
    const float* Km     = (const float*)d_in[2];
    const float* Pm     = (const float*)d_in[3];
    float* out_feat  = (float*)d_out;
    float* out_depth = (float*)d_out + (size_t)NPTS * CH;

    // ---- New path: needs tmp (16 MB) + featT (268 MB) --------------------
    const size_t tmp_off   = 0;
    const size_t featT_off = (size_t)NPTS * sizeof(Rec);                      // 16 MB
    const size_t featT_sz  = (size_t)BATCH * CH * IMG * IMG * sizeof(float);  // 268 MB
    const size_t need_new  = featT_off + featT_sz;

    if (ws_size >= need_new) {
        Rec*   tmp   = (Rec*)((char*)d_ws + tmp_off);
        float* featT = (float*)((char*)d_ws + featT_off);
        pass_project<<<NPTS / 256, 256, 0, stream>>>(coords, Km, Pm, tmp, out_depth);
        pass_transpose<<<BATCH * IMG * (IMG / 128), 256, 0, stream>>>(feat, featT);
        pass_gather_t<<<NPTS / 16, 256, 0, stream>>>(tmp, featT, out_feat);
        return;
    }

    // ---- Fallback 1: previous binned pipeline ----------------------------
    const size_t counts_off = 0;
    const size_t cursor_off = 4096;
    const size_t tmp2_off   = 16384;
    const size_t recs_off   = 16384 + (size_t)NPTS * sizeof(Rec);
    const size_t need_old   = recs_off + (size_t)NPTS * sizeof(Rec);

    if (ws_size >= need_old) {
        uint32_t* counts = (uint32_t*)((char*)d_ws + counts_off);
        uint32_t* cursor = (uint32_t*)((char*)d_ws + cursor_off);
        Rec*      tmp    = (Rec*)((char*)d_ws + tmp2_off);
        Rec*      recs   = (Rec*)((char*)d_ws + recs_off);

        pass_zero<<<1, NBINS, 0, stream>>>(counts);
        pass_hist<<<NPTS / 256, 256, 0, stream>>>(coords, Km, Pm, counts, tmp, out_depth);
        pass_scan<<<1, NBINS, 0, stream>>>(counts, cursor);
        pass_scatter<<<NPTS / 256, 256, 0, stream>>>(tmp, cursor, recs);
        pass_gather<<<NBLK_D, 256, 0, stream>>>(recs, feat, out_feat);
        return;
    }

    // ---- Fallback 2: unbinned single pass --------------------------------
    const long long total = (long long)NPTS * 64;
    gs_tok<<<(int)((total + 255) / 256), 256, 0, stream>>>(
        coords, feat, Km, Pm, out_feat, out_depth);
}

// Round 2
// 548.265 us; speedup vs baseline: 2.6052x; 1.1352x over previous
//
#include <hip/hip_runtime.h>
#include <hip/hip_fp16.h>
#include <stdint.h>

#define GRID_RES 64
#define NPTS 1048576
#define CH 64
#define IMG 512
#define BATCH 4
#define NBINS 1024              // fallback path: 4 batches x 16 x 16 tiles of 32x32 px
#define NBLK_D (NPTS / 4)       // fallback gather: 4 points (waves) per 256-thr block
#define CHUNKS_PER_XCD (NBLK_D / 8)

struct Rec { float di, dj; uint32_t meta, pt; };

__device__ __forceinline__ void project_point(
    const int4 cd, const float* __restrict__ Km, const float* __restrict__ Pm,
    float& di, float& dj, int& i0, int& i1, int& j0, int& j1, int& b, float& cz_out)
{
    b = cd.x;
    const float s = 2.0f / (GRID_RES - 1);
    float wx = (float)cd.y * s - 1.0f;
    float wy = (float)cd.z * s - 1.0f;
    float wz = (float)cd.w * s - 1.0f;

    float cx = Pm[0]*wx  + Pm[1]*wy  + Pm[2]*wz  + Pm[3];
    float cy = Pm[4]*wx  + Pm[5]*wy  + Pm[6]*wz  + Pm[7];
    float cz = Pm[8]*wx  + Pm[9]*wy  + Pm[10]*wz + Pm[11];
    float cw = Pm[12]*wx + Pm[13]*wy + Pm[14]*wz + Pm[15];
    cx = cx / cw; cy = cy / cw; cz = cz / cw;

    float ix = Km[0]*cx + Km[1]*cy + Km[2]*cz;
    float iy = Km[3]*cx + Km[4]*cy + Km[5]*cz;
    float iz = Km[6]*cx + Km[7]*cy + Km[8]*cz;
    float x = ix / iz;
    float y = iy / iz;

    float fi = floorf(y);
    float fj = floorf(x);
    di = y - fi;
    dj = x - fj;
    i0 = min(max((int)fi, 0), IMG - 1);
    i1 = min(max((int)fi + 1, 0), IMG - 1);
    j0 = min(max((int)fj, 0), IMG - 1);
    j1 = min(max((int)fj + 1, 0), IMG - 1);
    cz_out = cz;
}

// ===========================================================================
// NEW PATH (2 launches):
//   L1: transpose (B,C,H,W) f32 -> (B,H,W,C) f16   (featT fits L3: 134 MB)
//   L2: fused project + gather (readlane-broadcast, scalar-based loads)
// ===========================================================================

// ---- L1: transpose + downconvert -----------------------------------------
// Block = one (b, row i, 128-px quarter). Tile = 128 px x 64 ch.
// Loads: 2x float2/lane from two adjacent channel planes (coalesced 512 B
// per wave per plane). LDS: half2 packed stores (4 B), half4 (8 B) reads.
// Stores: 8 B/lane, 512 B contiguous per wave instruction.
__global__ __launch_bounds__(256) void pass_transpose_h(
    const float* __restrict__ feat, __half* __restrict__ featT)
{
    __shared__ __half lds[128 * 68];   // row stride 68 halfs = 136 B (8B-aligned)
    const int t   = threadIdx.x;
    const int blk = blockIdx.x;
    const int q = blk & 3;             // 128-px quarter
    const int i = (blk >> 2) & 511;    // image row
    const int b = blk >> 11;           // batch
    const int j0 = q << 7;

    const int px2 = (t & 63) << 1;     // pixel pair within quarter
    const int c0  = (t >> 6) << 1;     // wave -> channel pair base 0,2,4,6
    const float* src = feat + ((size_t)(b * CH + c0) << 18)
                            + ((size_t)i << 9) + j0 + px2;
    #pragma unroll
    for (int k = 0; k < 8; ++k) {
        const float* s0 = src + ((size_t)(k * 8) << 18);
        float2 v0 = *(const float2*)(s0);                 // channel c0+8k
        float2 v1 = *(const float2*)(s0 + (1u << 18));    // channel c0+8k+1
        int cc = c0 + k * 8;
        *(__half2*)&lds[(px2 + 0) * 68 + cc] = __floats2half2_rn(v0.x, v1.x);
        *(__half2*)&lds[(px2 + 1) * 68 + cc] = __floats2half2_rn(v0.y, v1.y);
    }
    __syncthreads();

    const int c4    = (t & 15) << 2;   // 16 lanes cover 64 channels (8 B each)
    const int pbase = t >> 4;
    __half* dst = featT + ((size_t)b << 24) + ((size_t)i << 15)
                        + ((size_t)j0 << 6) + c4;
    #pragma unroll
    for (int m = 0; m < 8; ++m) {
        int pix = pbase + (m << 4);
        *(uint2*)(dst + ((size_t)pix << 6)) = *(const uint2*)&lds[pix * 68 + c4];
    }
}

// ---- L2: fused project + gather ------------------------------------------
// Wave = 64 consecutive points. Phase 1: lane = point -> project, write
// depth coalesced. Phase 2: lane = channel; 64 fully-unrolled iterations,
// per-point meta/di/dj broadcast to SGPRs via readlane -> scalar address
// decode, fp16 corner loads (128 B/wave each), f32 bilinear, coalesced
// 256 B/wave stores.
__global__ __launch_bounds__(256, 4) void pass_gather_h(
    const int* __restrict__ coords, const float* __restrict__ Km,
    const float* __restrict__ Pm, const __half* __restrict__ featT,
    float* __restrict__ out_feat, float* __restrict__ out_depth)
{
    const uint32_t wave = blockIdx.x * 4u + (threadIdx.x >> 6);
    const uint32_t p0 = wave << 6;
    const int lane = threadIdx.x & 63;
    const int c = lane;

    // ---- phase 1: per-lane projection of point p0+lane ----
    const int4 cd = ((const int4*)coords)[p0 + lane];
    float di, dj, cz; int i0, i1, j0, j1, b;
    project_point(cd, Km, Pm, di, dj, i0, i1, j0, j1, b, cz);
    out_depth[p0 + lane] = cz;

    uint32_t meta = ((uint32_t)b << 20) | ((uint32_t)i0 << 11) | ((uint32_t)j0 << 2)
                  | ((uint32_t)(i1 - i0) << 1) | (uint32_t)(j1 - j0);
    uint32_t dib = __float_as_uint(di);
    uint32_t djb = __float_as_uint(dj);

    float* outp = out_feat + (((size_t)p0) << 6) + c;

    // ---- phase 2: gather 64 points, lane = channel ----
    #pragma unroll
    for (int u = 0; u < 64; ++u) {
        uint32_t m  = __builtin_amdgcn_readlane(meta, u);
        float diu = __uint_as_float(__builtin_amdgcn_readlane(dib, u));
        float dju = __uint_as_float(__builtin_amdgcn_readlane(djb, u));
        int j1d = m & 1;
        int i1d = (m >> 1) & 1;
        uint32_t off = ((m >> 2) & 511u) << 6;    // j0
        off += ((m >> 11) & 511u) << 15;          // i0
        off += (m >> 20) << 24;                   // b
        const __half* base = featT + off + c;
        float f00 = __half2float(base[0]);
        float f01 = __half2float(base[j1d << 6]);
        float f10 = __half2float(base[i1d << 15]);
        float f11 = __half2float(base[(i1d << 15) + (j1d << 6)]);
        float omdi = 1.0f - diu;
        float mj  = omdi * f00 + diu * f10;
        float mjp = omdi * f01 + diu * f11;
        outp[(size_t)u << 6] = (1.0f - dju) * mj + dju * mjp;
    }
}

// ===========================================================================
// FALLBACK 1: binned f32 pipeline (ws >= 48 MB but < 134 MB)
// ===========================================================================

__global__ void pass_zero(uint32_t* counts) {
    counts[threadIdx.x] = 0;   // 1 block x 1024 threads
}

__global__ __launch_bounds__(256) void pass_hist(
    const int* __restrict__ coords, const float* __restrict__ Km,
    const float* __restrict__ Pm, uint32_t* __restrict__ counts,
    Rec* __restrict__ tmp, float* __restrict__ out_depth)
{
    __shared__ uint32_t h[NBINS];
    for (int i = threadIdx.x; i < NBINS; i += 256) h[i] = 0;
    __syncthreads();

    int pt = blockIdx.x * 256 + threadIdx.x;
    const int4 cd = ((const int4*)coords)[pt];
    float di, dj, cz; int i0, i1, j0, j1, b;
    project_point(cd, Km, Pm, di, dj, i0, i1, j0, j1, b, cz);

    Rec r;
    r.di = di; r.dj = dj;
    r.meta = ((uint32_t)b << 20) | ((uint32_t)i0 << 11) | ((uint32_t)j0 << 2)
           | ((uint32_t)(i1 - i0) << 1) | (uint32_t)(j1 - j0);
    r.pt = (uint32_t)pt;
    tmp[pt] = r;
    out_depth[pt] = cz;

    int bin = (b << 8) | ((i0 >> 5) << 4) | (j0 >> 5);
    atomicAdd(&h[bin], 1u);
    __syncthreads();
    for (int i = threadIdx.x; i < NBINS; i += 256)
        if (h[i]) atomicAdd(&counts[i], h[i]);
}

__global__ void pass_scan(const uint32_t* __restrict__ counts, uint32_t* __restrict__ cursor) {
    __shared__ uint32_t a[NBINS];
    int t = threadIdx.x;            // 1 block x 1024 threads
    a[t] = counts[t];
    __syncthreads();
    for (int off = 1; off < NBINS; off <<= 1) {
        uint32_t v = a[t];
        uint32_t add = (t >= off) ? a[t - off] : 0u;
        __syncthreads();
        a[t] = v + add;
        __syncthreads();
    }
    cursor[t] = (t == 0) ? 0u : a[t - 1];
}

__global__ __launch_bounds__(256) void pass_scatter(
    const Rec* __restrict__ tmp, uint32_t* __restrict__ cursor, Rec* __restrict__ recs)
{
    int pt = blockIdx.x * 256 + threadIdx.x;
    Rec r = tmp[pt];
    int i0 = (r.meta >> 11) & 511;
    int j0 = (r.meta >> 2) & 511;
    int b  = r.meta >> 20;
    int bin = (b << 8) | ((i0 >> 5) << 4) | (j0 >> 5);
    uint32_t pos = atomicAdd(&cursor[bin], 1u);
    recs[pos] = r;
}

__global__ __launch_bounds__(256) void pass_gather(
    const Rec* __restrict__ recs, const float* __restrict__ feat,
    float* __restrict__ out_feat)
{
    uint32_t bi = blockIdx.x;
    uint32_t chunk = (bi & 7u) * CHUNKS_PER_XCD + (bi >> 3);
    uint32_t p = chunk * 4u + (threadIdx.x >> 6);
    int c = threadIdx.x & 63;

    Rec r = recs[p];
    int j1d = r.meta & 1;
    int i1d = (r.meta >> 1) & 1;
    int j0  = (r.meta >> 2) & 511;
    int i0  = (r.meta >> 11) & 511;
    int b   = r.meta >> 20;

    const float* base = feat + ((size_t)(b * CH + c) << 18);
    const float* r0 = base + (i0 << 9);
    const float* r1 = r0 + (i1d << 9);
    float f00 = r0[j0];
    float f01 = r0[j0 + j1d];
    float f10 = r1[j0];
    float f11 = r1[j0 + j1d];

    float omdi = 1.0f - r.di;
    float mj  = omdi * f00 + r.di * f10;
    float mjp = omdi * f01 + r.di * f11;
    float res = (1.0f - r.dj) * mj + r.dj * mjp;

    out_feat[(size_t)r.pt * CH + c] = res;
}

// ===========================================================================
// FALLBACK 2: round-1 kernel (ws too small for anything)
// ===========================================================================
__global__ __launch_bounds__(256) void gs_tok(
    const int* __restrict__ coords, const float* __restrict__ feat,
    const float* __restrict__ Km, const float* __restrict__ Pm,
    float* __restrict__ out_feat, float* __restrict__ out_depth)
{
    int t = blockIdx.x * blockDim.x + threadIdx.x;
    int point = t >> 6;
    int c = t & 63;
    if (point >= NPTS) return;
    const int4 cd = ((const int4*)coords)[point];
    float di, dj, cz; int i0, i1, j0, j1, b;
    project_point(cd, Km, Pm, di, dj, i0, i1, j0, j1, b, cz);
    const float* base = feat + ((size_t)(b * CH + c) << 18);
    const float* r0 = base + (i0 << 9);
    const float* r1 = base + (i1 << 9);
    float f00 = r0[j0], f01 = r0[j1], f10 = r1[j0], f11 = r1[j1];
    float omdi = 1.0f - di;
    float mj  = omdi * f00 + di * f10;
    float mjp = omdi * f01 + di * f11;
    float res = (1.0f - dj) * mj + dj * mjp;
    out_feat[(size_t)point * CH + c] = res;
    if (c == 0) out_depth[point] = cz;
}

extern "C" void kernel_launch(void* const* d_in, const int* in_sizes, int n_in,
                              void* d_out, int out_size, void* d_ws, size_t ws_size,
                              hipStream_t stream)
{
    const int*   coords = (const int*)d_in[0];
    const float* feat   = (const float*)d_in[1];
    const float* Km     = (const float*)d_in[2];
    const float* Pm     = (const float*)d_in[3];
    float* out_feat  = (float*)d_out;
    float* out_depth = (float*)d_out + (size_t)NPTS * CH;

    // ---- New path: needs featT f16 (134 MB) ------------------------------
    const size_t featT_sz = (size_t)BATCH * CH * IMG * IMG * sizeof(__half); // 134 MB

    if (ws_size >= featT_sz) {
        __half* featT = (__half*)d_ws;
        pass_transpose_h<<<BATCH * IMG * (IMG / 128), 256, 0, stream>>>(feat, featT);
        pass_gather_h<<<NPTS / 256, 256, 0, stream>>>(
            coords, Km, Pm, featT, out_feat, out_depth);
        return;
    }

    // ---- Fallback 1: binned f32 pipeline ---------------------------------
    const size_t counts_off = 0;
    const size_t cursor_off = 4096;
    const size_t tmp2_off   = 16384;
    const size_t recs_off   = 16384 + (size_t)NPTS * sizeof(Rec);
    const size_t need_old   = recs_off + (size_t)NPTS * sizeof(Rec);

    if (ws_size >= need_old) {
        uint32_t* counts = (uint32_t*)((char*)d_ws + counts_off);
        uint32_t* cursor = (uint32_t*)((char*)d_ws + cursor_off);
        Rec*      tmp    = (Rec*)((char*)d_ws + tmp2_off);
        Rec*      recs   = (Rec*)((char*)d_ws + recs_off);

        pass_zero<<<1, NBINS, 0, stream>>>(counts);
        pass_hist<<<NPTS / 256, 256, 0, stream>>>(coords, Km, Pm, counts, tmp, out_depth);
        pass_scan<<<1, NBINS, 0, stream>>>(counts, cursor);
        pass_scatter<<<NPTS / 256, 256, 0, stream>>>(tmp, cursor, recs);
        pass_gather<<<NBLK_D, 256, 0, stream>>>(recs, feat, out_feat);
        return;
    }

    // ---- Fallback 2: unbinned single pass --------------------------------
    const long long total = (long long)NPTS * 64;
    gs_tok<<<(int)((total + 255) / 256), 256, 0, stream>>>(
        coords, feat, Km, Pm, out_feat, out_depth);
}